// Round 10
// baseline (322.417 us; speedup 1.0000x reference)
//
#include <hip/hip_runtime.h>
#include <cstdint>
#include <cstddef>

#define NN 100000
#define NE 1600000
#define DD 64
#define NG 64

#define EPB 4096
#define NBLK ((NE + EPB - 1) / EPB)      // 391
#define NBUCK ((NN + 511) / 512)         // 196
#define BCAP 10240
#define NTILE (NN / 16)                  // 6250
#define NBT ((NTILE + 3) / 4)            // 1563 blocks, 4 independent waves each

typedef unsigned short u16;
typedef unsigned int u32;
typedef unsigned char u8;
typedef short short8 __attribute__((ext_vector_type(8)));
typedef float f32x4 __attribute__((ext_vector_type(4)));
typedef float f32x2 __attribute__((ext_vector_type(2)));

__device__ __forceinline__ float bf2f(u16 h) {
    u32 u = ((u32)h) << 16;
    return __builtin_bit_cast(float, u);
}
__device__ __forceinline__ u16 f2bf(float f) {
    u32 u = __builtin_bit_cast(u32, f);
    u += 0x7fffu + ((u >> 16) & 1u);
    return (u16)(u >> 16);
}

// ---------------- CSR build: bucket partition, all-coalesced writes --------
__global__ void __launch_bounds__(256) k_hist(const int* __restrict__ dst,
                                              int* __restrict__ hist) {
    __shared__ int h[NBUCK];
    for (int i = threadIdx.x; i < NBUCK; i += 256) h[i] = 0;
    __syncthreads();
    const int base = blockIdx.x * EPB;
    const int end = (base + EPB < NE) ? base + EPB : NE;
    for (int i = base + threadIdx.x; i < end; i += 256)
        atomicAdd(&h[dst[i] >> 9], 1);
    __syncthreads();
    for (int i = threadIdx.x; i < NBUCK; i += 256)
        hist[i * NBLK + blockIdx.x] = h[i];
}

__global__ void __launch_bounds__(512) k_rowscan(int* __restrict__ hist,
                                                 int* __restrict__ btot) {
    __shared__ int s[2][512];
    const int b = blockIdx.x;
    const int t = threadIdx.x;
    int v = (t < NBLK) ? hist[b * NBLK + t] : 0;
    s[0][t] = v;
    __syncthreads();
    int sel = 0;
    for (int off = 1; off < 512; off <<= 1) {
        int x = s[sel][t];
        if (t >= off) x += s[sel][t - off];
        s[sel ^ 1][t] = x;
        __syncthreads();
        sel ^= 1;
    }
    if (t < NBLK) hist[b * NBLK + t] = s[sel][t] - v;
    if (t == 511) btot[b] = s[sel][511];
}

__global__ void __launch_bounds__(256) k_btscan(int* __restrict__ btot) {
    __shared__ int s[2][256];
    const int t = threadIdx.x;
    int v = (t < NBUCK) ? btot[t] : 0;
    s[0][t] = v;
    __syncthreads();
    int sel = 0;
    for (int off = 1; off < 256; off <<= 1) {
        int x = s[sel][t];
        if (t >= off) x += s[sel][t - off];
        s[sel ^ 1][t] = x;
        __syncthreads();
        sel ^= 1;
    }
    if (t < NBUCK) btot[t] = s[sel][t] - v;
    if (t == 0) btot[NBUCK] = NE;
}

__global__ void __launch_bounds__(256) k_part(const int* __restrict__ src,
                                              const int* __restrict__ dst,
                                              const int* __restrict__ excl,
                                              const int* __restrict__ btot,
                                              u32* __restrict__ part) {
    __shared__ int cnt[NBUCK];
    __shared__ int diff[NBUCK];
    __shared__ int cur[NBUCK];
    __shared__ int sc[2][256];
    __shared__ u32 pk[EPB];
    __shared__ u8  bk[EPB];
    const int t = threadIdx.x;
    const int blk = blockIdx.x;
    const int base = blk * EPB;
    const int n = ((base + EPB < NE) ? EPB : NE - base);
    for (int i = t; i < NBUCK; i += 256) cnt[i] = 0;
    __syncthreads();

    int myb[EPB / 256];
    u32 mypk[EPB / 256];
#pragma unroll
    for (int j = 0; j < EPB / 256; ++j) {
        int i = t + j * 256;
        bool ok = i < n;
        int d = ok ? dst[base + i] : 0;
        int s2 = ok ? src[base + i] : 0;
        int b = d >> 9;
        myb[j] = b;
        mypk[j] = ((u32)(d & 511) << 17) | (u32)s2;
        if (ok) atomicAdd(&cnt[b], 1);
    }
    __syncthreads();
    int v = (t < NBUCK) ? cnt[t] : 0;
    sc[0][t] = v;
    __syncthreads();
    int sel = 0;
    for (int off = 1; off < 256; off <<= 1) {
        int x = sc[sel][t];
        if (t >= off) x += sc[sel][t - off];
        sc[sel ^ 1][t] = x;
        __syncthreads();
        sel ^= 1;
    }
    if (t < NBUCK) {
        int e = sc[sel][t] - v;
        cur[t] = e;
        diff[t] = excl[t * NBLK + blk] + btot[t] - e;
    }
    __syncthreads();
#pragma unroll
    for (int j = 0; j < EPB / 256; ++j) {
        int i = t + j * 256;
        if (i < n) {
            int pos = atomicAdd(&cur[myb[j]], 1);
            pk[pos] = mypk[j];
            bk[pos] = (u8)myb[j];
        }
    }
    __syncthreads();
    for (int p = t; p < n; p += 256)
        part[diff[bk[p]] + p] = pk[p];
}

__global__ void __launch_bounds__(512) k_bucket(const u32* __restrict__ part,
                                                const int* __restrict__ btot,
                                                int* __restrict__ row_off,
                                                int* __restrict__ srcs,
                                                float* __restrict__ deg_inv) {
    __shared__ int cnt[512];
    __shared__ int cur[512];
    __shared__ int sc[2][512];
    __shared__ int lsrc[BCAP];
    const int b = blockIdx.x;
    const int t = threadIdx.x;
    const int base = btot[b];
    const int endp = btot[b + 1];
    const int n = endp - base;
    cnt[t] = 0;
    __syncthreads();
    for (int i = t; i < n; i += 512)
        atomicAdd(&cnt[part[base + i] >> 17], 1);
    __syncthreads();
    int v = cnt[t];
    sc[0][t] = v;
    __syncthreads();
    int sel = 0;
    for (int off = 1; off < 512; off <<= 1) {
        int x = sc[sel][t];
        if (t >= off) x += sc[sel][t - off];
        sc[sel ^ 1][t] = x;
        __syncthreads();
        sel ^= 1;
    }
    const int el = sc[sel][t] - v;
    const int g = b * 512 + t;
    if (g < NN) {
        row_off[g] = base + el;
        deg_inv[g] = (v > 0) ? 1.0f / (float)v : 0.0f;
    }
    if (b == NBUCK - 1 && t == 0) row_off[NN] = NE;
    cur[t] = el;
    __syncthreads();
    for (int i = t; i < n; i += 512) {
        u32 p = part[base + i];
        int pos = atomicAdd(&cur[p >> 17], 1);
        int s2 = (int)(p & 0x1FFFFu);
        if (pos < BCAP) lsrc[pos] = s2;
        else srcs[base + pos] = s2;
    }
    __syncthreads();
    const int lim = (n < BCAP) ? n : BCAP;
    for (int i = t; i < lim; i += 512)
        srcs[base + i] = lsrc[i];
}

// -- fp32 -> bf16 (features, weights) + fp8 HALF-PLANES (gather tables) -----
__global__ void k_cvtall(const float* __restrict__ x, u16* __restrict__ xb,
                         u8* __restrict__ x8a, u8* __restrict__ x8b,
                         u8* __restrict__ hA8a, u8* __restrict__ hA8b,
                         u8* __restrict__ hB8a, u8* __restrict__ hB8b,
                         const float* __restrict__ w0, const float* __restrict__ w1,
                         const float* __restrict__ w2, const float* __restrict__ w3,
                         const float* __restrict__ w4, const float* __restrict__ w5,
                         u16* __restrict__ wbuf) {
    // zero sentinel half-rows (node NN) of all six fp8 planes
    if (blockIdx.x == 0 && threadIdx.x < 48) {
        int pl = threadIdx.x >> 3, w = threadIdx.x & 7;
        u8* tb = (pl == 0) ? x8a : (pl == 1) ? x8b : (pl == 2) ? hA8a
               : (pl == 3) ? hA8b : (pl == 4) ? hB8a : hB8b;
        *(u32*)&tb[(size_t)NN * 32 + w * 4] = 0u;
    }
    int i = blockIdx.x * blockDim.x + threadIdx.x;
    int stride = gridDim.x * blockDim.x;
    const int total = NN * DD / 4;   // feature quads
    const int wt4 = 6 * 4096 / 4;    // weight quads
    for (; i < total + wt4; i += stride) {
        if (i < total) {
            float4 v = *(const float4*)&x[(size_t)i * 4];
            uint2 pk;
            pk.x = (u32)f2bf(v.x) | ((u32)f2bf(v.y) << 16);
            pk.y = (u32)f2bf(v.z) | ((u32)f2bf(v.w) << 16);
            ((uint2*)xb)[i] = pk;
            u32 lo = (u32)__builtin_amdgcn_cvt_pk_fp8_f32(v.x, v.y, 0, false);
            u32 q8 = (u32)__builtin_amdgcn_cvt_pk_fp8_f32(v.z, v.w, (int)lo, true);
            int node = i >> 4, q = i & 15;
            if (q < 8) ((u32*)x8a)[node * 8 + q] = q8;
            else       ((u32*)x8b)[node * 8 + q - 8] = q8;
        } else {
            int k = (i - total) * 4;
            int m = k >> 12;
            const float* W = (m == 0) ? w0 : (m == 1) ? w1 : (m == 2) ? w2
                           : (m == 3) ? w3 : (m == 4) ? w4 : w5;
            float4 v = *(const float4*)&W[k & 4095];
            uint2 pk;
            pk.x = (u32)f2bf(v.x) | ((u32)f2bf(v.y) << 16);
            pk.y = (u32)f2bf(v.z) | ((u32)f2bf(v.w) << 16);
            ((uint2*)wbuf)[i - total] = pk;
        }
    }
}

// ---------------- fused layer: two-pass fp8 gather + dual bf16 MFMA --------
// One INDEPENDENT wave per 16-node tile. fp8 features live in TWO half-
// feature planes (3.2 MB each -> per-XCD L2-resident per pass). Ids for all
// 16 nodes staged once in LDS, reused by both passes. Two nodes gathered
// concurrently for 4 loads in flight. MFMA phase = R8 (bf16 x-term/weights).
__global__ void __launch_bounds__(256) k_fused(
    const u16* __restrict__ hinb,
    const u8* __restrict__ hin8a, const u8* __restrict__ hin8b,
    u16* __restrict__ hout, u8* __restrict__ hout8a, u8* __restrict__ hout8b,
    const u16* __restrict__ wb,   // [2][4096] bf16: Wl, Wr
    const float* __restrict__ bl,
    const int* __restrict__ row_off, const int* __restrict__ srcs,
    const float* __restrict__ deg_inv, int relu, int mode) {
    __shared__ int idsL[4][16][64];              // 16 KB
    __shared__ int4 metaL[4][16];                // beg, deg, dinv
    __shared__ int scratch[4][64];
    __shared__ __align__(16) u8 aggT[4][2048];   // 16 rows x 128B bf16, swizzled
    const int tid  = threadIdx.x;
    const int lane = tid & 63;
    const int wid  = tid >> 6;
    const int oct  = lane >> 3;        // row octet 0..7
    const int f4   = (lane & 7) * 4;   // fp8 byte base within 32B half-row
    const int tile = blockIdx.x * 4 + wid;
    if (tile >= NTILE) return;
    const int n0 = tile * 16;

    // ---- stage ids + meta for all 16 nodes (reused by both passes) ----
    for (int j = 0; j < 16; ++j) {
        int b = row_off[n0 + j], e = row_off[n0 + j + 1];
        idsL[wid][j][lane] = (b + lane < e) ? srcs[b + lane] : NN;
        if (lane == 0)
            metaL[wid][j] = make_int4(b, e - b,
                __builtin_bit_cast(int, deg_inv[n0 + j]), 0);
    }
    __builtin_amdgcn_wave_barrier();

#define OCT(IDS, J, A01, A23) { \
        int _id = (IDS)[(J) + oct]; \
        u32 _v = *(const u32*)&plane[(size_t)_id * 32 + f4]; \
        A01 += __builtin_amdgcn_cvt_pk_f32_fp8(_v, false); \
        A23 += __builtin_amdgcn_cvt_pk_f32_fp8(_v, true); }

    // ---- two gather passes over the half-feature planes ----
    for (int p = 0; p < 2; ++p) {
        const u8* __restrict__ plane = p ? hin8b : hin8a;
        for (int jj = 0; jj < 16; jj += 2) {
            const int* idsA = &idsL[wid][jj][0];
            const int* idsB = &idsL[wid][jj + 1][0];
            int4 mA = metaL[wid][jj];
            int4 mB = metaL[wid][jj + 1];
            int cA = mA.y < 64 ? mA.y : 64;
            int cB = mB.y < 64 ? mB.y : 64;
            int cmx = cA > cB ? cA : cB;
            f32x2 a01 = {0.f, 0.f}, a23 = {0.f, 0.f};
            f32x2 b01 = {0.f, 0.f}, b23 = {0.f, 0.f};
            for (int jq = 0; jq < cmx; jq += 8) {   // sentinel-padded
                OCT(idsA, jq, a01, a23)
                OCT(idsB, jq, b01, b23)
            }
            if (mA.y > 64) {                        // rare deg>64 fallback
                for (int b2 = 64; b2 < mA.y; b2 += 64) {
                    __builtin_amdgcn_wave_barrier();
                    scratch[wid][lane] = (b2 + lane < mA.y) ? srcs[mA.x + b2 + lane] : NN;
                    __builtin_amdgcn_wave_barrier();
                    int mm = mA.y - b2; if (mm > 64) mm = 64;
                    for (int jq = 0; jq < mm; jq += 8)
                        OCT(&scratch[wid][0], jq, a01, a23)
                }
            }
            if (mB.y > 64) {
                for (int b2 = 64; b2 < mB.y; b2 += 64) {
                    __builtin_amdgcn_wave_barrier();
                    scratch[wid][lane] = (b2 + lane < mB.y) ? srcs[mB.x + b2 + lane] : NN;
                    __builtin_amdgcn_wave_barrier();
                    int mm = mB.y - b2; if (mm > 64) mm = 64;
                    for (int jq = 0; jq < mm; jq += 8)
                        OCT(&scratch[wid][0], jq, b01, b23)
                }
            }
            // reduce across the 8 row-octets (lane bits 3..5)
            float s0 = a01.x, s1 = a01.y, s2 = a23.x, s3 = a23.y;
            float t0 = b01.x, t1 = b01.y, t2 = b23.x, t3 = b23.y;
#pragma unroll
            for (int m = 8; m <= 32; m <<= 1) {
                s0 += __shfl_xor(s0, m); s1 += __shfl_xor(s1, m);
                s2 += __shfl_xor(s2, m); s3 += __shfl_xor(s3, m);
                t0 += __shfl_xor(t0, m); t1 += __shfl_xor(t1, m);
                t2 += __shfl_xor(t2, m); t3 += __shfl_xor(t3, m);
            }
            const float dA = __builtin_bit_cast(float, mA.z);
            const float dB = __builtin_bit_cast(float, mB.z);
            if (lane < 8) {
                uint2 pkA, pkB;
                pkA.x = (u32)f2bf(s0 * dA) | ((u32)f2bf(s1 * dA) << 16);
                pkA.y = (u32)f2bf(s2 * dA) | ((u32)f2bf(s3 * dA) << 16);
                pkB.x = (u32)f2bf(t0 * dB) | ((u32)f2bf(t1 * dB) << 16);
                pkB.y = (u32)f2bf(t2 * dB) | ((u32)f2bf(t3 * dB) << 16);
                const int cb = p * 64 + f4 * 2;
                *(uint2*)&aggT[wid][jj * 128 + (cb ^ ((jj & 7) << 4))] = pkA;
                *(uint2*)&aggT[wid][(jj + 1) * 128 + (cb ^ (((jj + 1) & 7) << 4))] = pkB;
            }
        }
    }
#undef OCT

    __builtin_amdgcn_wave_barrier();
    asm volatile("" ::: "memory");   // keep weight loads out of gather phase

    // ---- MFMA phase: wave's own 16-node tile (identical to R8) ----
    const int r = lane & 15, g = lane >> 4;
    f32x4 acc[4] = {};
#pragma unroll
    for (int kc = 0; kc < 2; ++kc) {
        const int cb = kc * 64 + g * 16;
        short8 aA = *(const short8*)&aggT[wid][r * 128 + (cb ^ ((r & 7) << 4))];
        short8 aH = *(const short8*)&hinb[(size_t)(n0 + r) * DD + kc * 32 + g * 8];
#pragma unroll
        for (int ct = 0; ct < 4; ++ct) {
            const int wrow = (ct * 16 + r) * DD + kc * 32 + g * 8;
            short8 bA = *(const short8*)&wb[wrow];
            short8 bH = *(const short8*)&wb[4096 + wrow];
            acc[ct] = __builtin_amdgcn_mfma_f32_16x16x32_bf16(aA, bA, acc[ct], 0, 0, 0);
            acc[ct] = __builtin_amdgcn_mfma_f32_16x16x32_bf16(aH, bH, acc[ct], 0, 0, 0);
        }
    }
#pragma unroll
    for (int ct = 0; ct < 4; ++ct) {
        float bias = bl[ct * 16 + r];
#pragma unroll
        for (int e = 0; e < 4; ++e) {
            float v = acc[ct][e] + bias;
            if (relu) v = fmaxf(v, 0.f);
            const size_t node = (size_t)(n0 + g * 4 + e);
            hout[node * DD + ct * 16 + r] = f2bf(v);
            if (mode == 0) {
                u8 q8 = (u8)((u32)__builtin_amdgcn_cvt_pk_fp8_f32(v, v, 0, false) & 0xffu);
                if (ct < 2) hout8a[node * 32 + ct * 16 + r] = q8;
                else        hout8b[node * 32 + (ct - 2) * 16 + r] = q8;
            }
        }
    }
}

// ---------------- graph readout ----------------
__global__ void k_reduce(const u16* __restrict__ h, const int* __restrict__ batch,
                         float* __restrict__ out) {
    const int lane = threadIdx.x & 63;
    const int wid  = threadIdx.x >> 6;
    const int gw   = blockIdx.x * 4 + wid;
    const int start = gw * 64;
    if (start >= NN) return;
    const int endn = (start + 64 < NN) ? start + 64 : NN;
    float acc = 0.f;
    int gcur = batch[start];
    for (int i = start; i < endn; ++i) {
        int g = batch[i];
        if (g != gcur) {
            atomicAdd(&out[gcur * DD + lane], acc);
            acc = 0.f;
            gcur = g;
        }
        acc += bf2f(h[(size_t)i * DD + lane]);
    }
    atomicAdd(&out[gcur * DD + lane], acc);
}

extern "C" void kernel_launch(void* const* d_in, const int* in_sizes, int n_in,
                              void* d_out, int out_size, void* d_ws, size_t ws_size,
                              hipStream_t stream) {
    const float* x     = (const float*)d_in[0];
    const int*   ei    = (const int*)d_in[1];
    const int*   batch = (const int*)d_in[2];
    const float* Wl[3] = {(const float*)d_in[3], (const float*)d_in[6], (const float*)d_in[9]};
    const float* bl[3] = {(const float*)d_in[4], (const float*)d_in[7], (const float*)d_in[10]};
    const float* Wr[3] = {(const float*)d_in[5], (const float*)d_in[8], (const float*)d_in[11]};
    float* out = (float*)d_out;

    char* ws = (char*)d_ws;
    size_t off = 0;
    auto alloc = [&](size_t bytes) -> void* {
        void* p = ws + off;
        off = (off + bytes + 255) & ~(size_t)255;
        return p;
    };
    int*   hist    = (int*)  alloc((size_t)NBUCK * NBLK * 4);
    int*   btot    = (int*)  alloc(((size_t)NBUCK + 1) * 4);
    float* deg_inv = (float*)alloc((size_t)NN * 4);
    int*   row_off = (int*)  alloc(((size_t)NN + 1) * 4);
    int*   srcs    = (int*)  alloc((size_t)NE * 4);
    u16*   wbuf    = (u16*)  alloc((size_t)6 * 4096 * 2);
    u16*   xb      = (u16*)  alloc((size_t)NN * DD * 2);
    u16*   hAb     = (u16*)  alloc((size_t)NN * DD * 2);
    u16*   hBb     = (u16*)  alloc((size_t)NN * DD * 2);
    u8*    x8a     = (u8*)   alloc(((size_t)NN + 1) * 32);  // half-feature planes
    u8*    x8b     = (u8*)   alloc(((size_t)NN + 1) * 32);  // (+1 sentinel row)
    u8*    hA8a    = (u8*)   alloc(((size_t)NN + 1) * 32);
    u8*    hA8b    = (u8*)   alloc(((size_t)NN + 1) * 32);
    u8*    hB8a    = (u8*)   alloc(((size_t)NN + 1) * 32);
    u8*    hB8b    = (u8*)   alloc(((size_t)NN + 1) * 32);
    // part aliases xb: k_part/k_bucket fully consume it before k_cvtall
    // writes xb (stream-ordered).
    u32*   part    = (u32*)xb;

    const int* e_src = ei;       // edge_index[0]
    const int* e_dst = ei + NE;  // edge_index[1]

    hipMemsetAsync(out, 0, (size_t)NG * DD * 4, stream);

    k_hist<<<NBLK, 256, 0, stream>>>(e_dst, hist);
    k_rowscan<<<NBUCK, 512, 0, stream>>>(hist, btot);
    k_btscan<<<1, 256, 0, stream>>>(btot);
    k_part<<<NBLK, 256, 0, stream>>>(e_src, e_dst, hist, btot, part);
    k_bucket<<<NBUCK, 512, 0, stream>>>(part, btot, row_off, srcs, deg_inv);
    k_cvtall<<<2048, 256, 0, stream>>>(x, xb, x8a, x8b, hA8a, hA8b, hB8a, hB8b,
                                       Wl[0], Wr[0], Wl[1], Wr[1], Wl[2], Wr[2], wbuf);

    k_fused<<<NBT, 256, 0, stream>>>(xb,  x8a,  x8b,  hAb, hA8a, hA8b,
                                     wbuf,            bl[0], row_off, srcs, deg_inv, 1, 0);
    k_fused<<<NBT, 256, 0, stream>>>(hAb, hA8a, hA8b, hBb, hB8a, hB8b,
                                     wbuf + 1 * 8192, bl[1], row_off, srcs, deg_inv, 1, 0);
    k_fused<<<NBT, 256, 0, stream>>>(hBb, hB8a, hB8b, hAb, x8a,  x8b,
                                     wbuf + 2 * 8192, bl[2], row_off, srcs, deg_inv, 0, 1);

    k_reduce<<<(NN / 64 + 4) / 4, 256, 0, stream>>>(hAb, batch, out);
}

// Round 11
// 202.474 us; speedup vs baseline: 1.5924x; 1.5924x over previous
//
#include <hip/hip_runtime.h>
#include <cstdint>
#include <cstddef>

#define NN 100000
#define NE 1600000
#define DD 64
#define NG 64

#define EPB 4096
#define NBLK ((NE + EPB - 1) / EPB)      // 391
#define NBUCK ((NN + 511) / 512)         // 196
#define BSTRIDE 12288                    // fixed per-bucket region in part[]
#define BCAP 10240
#define NTILE (NN / 16)                  // 6250
#define NBT ((NTILE + 3) / 4)            // 1563 blocks, 4 independent waves each

typedef unsigned short u16;
typedef unsigned int u32;
typedef unsigned char u8;
typedef short short8 __attribute__((ext_vector_type(8)));
typedef float f32x4 __attribute__((ext_vector_type(4)));
typedef float f32x2 __attribute__((ext_vector_type(2)));

__device__ __forceinline__ float bf2f(u16 h) {
    u32 u = ((u32)h) << 16;
    return __builtin_bit_cast(float, u);
}
__device__ __forceinline__ u16 f2bf(float f) {
    u32 u = __builtin_bit_cast(u32, f);
    u += 0x7fffu + ((u >> 16) & 1u);
    return (u16)(u >> 16);
}

// ---- CSR build, 2 kernels: bucket-partition with global atomic cursors ----
// k_part2: one pass over edges. Per-block LDS bucket histogram + local scan
// (for LDS grouping), one atomicAdd per (block,bucket) to global cursors for
// the write base, coalesced streamed writes into fixed-stride bucket regions.
__global__ void __launch_bounds__(256) k_part2(const int* __restrict__ src,
                                               const int* __restrict__ dst,
                                               int* __restrict__ gcur,
                                               u32* __restrict__ part) {
    __shared__ int cnt[NBUCK];
    __shared__ int diff[NBUCK];
    __shared__ int cur[NBUCK];
    __shared__ int sc[2][256];
    __shared__ u32 pk[EPB];
    __shared__ u8  bk[EPB];
    const int t = threadIdx.x;
    const int blk = blockIdx.x;
    const int base = blk * EPB;
    const int n = ((base + EPB < NE) ? EPB : NE - base);
    for (int i = t; i < NBUCK; i += 256) cnt[i] = 0;
    __syncthreads();

    int myb[EPB / 256];
    u32 mypk[EPB / 256];
#pragma unroll
    for (int j = 0; j < EPB / 256; ++j) {
        int i = t + j * 256;
        bool ok = i < n;
        int d = ok ? dst[base + i] : 0;
        int s2 = ok ? src[base + i] : 0;
        int b = d >> 9;
        myb[j] = b;
        mypk[j] = ((u32)(d & 511) << 17) | (u32)s2;
        if (ok) atomicAdd(&cnt[b], 1);
    }
    __syncthreads();
    int v = (t < NBUCK) ? cnt[t] : 0;
    sc[0][t] = v;
    __syncthreads();
    int sel = 0;
    for (int off = 1; off < 256; off <<= 1) {
        int x = sc[sel][t];
        if (t >= off) x += sc[sel][t - off];
        sc[sel ^ 1][t] = x;
        __syncthreads();
        sel ^= 1;
    }
    if (t < NBUCK) {
        int e = sc[sel][t] - v;                         // local exclusive offset
        cur[t] = e;
        int gbase = (v > 0) ? atomicAdd(&gcur[t], v) : 0;
        diff[t] = t * BSTRIDE + gbase - e;
    }
    __syncthreads();
#pragma unroll
    for (int j = 0; j < EPB / 256; ++j) {
        int i = t + j * 256;
        if (i < n) {
            int pos = atomicAdd(&cur[myb[j]], 1);
            pk[pos] = mypk[j];
            bk[pos] = (u8)myb[j];
        }
    }
    __syncthreads();
    for (int p = t; p < n; p += 256)
        part[diff[bk[p]] + p] = pk[p];
}

// k_bucket2: per bucket, compute dense base by scanning the 196 final
// cursor counts in LDS, then per-dst counts -> row_off/deg_inv (coalesced),
// LDS scatter of srcs sorted by dst, coalesced flush.
__global__ void __launch_bounds__(512) k_bucket2(const u32* __restrict__ part,
                                                 const int* __restrict__ gcnt,
                                                 int* __restrict__ row_off,
                                                 int* __restrict__ srcs,
                                                 float* __restrict__ deg_inv) {
    __shared__ int cnt[512];
    __shared__ int cur[512];
    __shared__ int sc[2][512];
    __shared__ int lsrc[BCAP];
    const int b = blockIdx.x;
    const int t = threadIdx.x;

    // inclusive scan of bucket counts -> this bucket's dense base
    int gv = (t < NBUCK) ? gcnt[t] : 0;
    sc[0][t] = gv;
    __syncthreads();
    int sel = 0;
    for (int off = 1; off < 512; off <<= 1) {
        int x = sc[sel][t];
        if (t >= off) x += sc[sel][t - off];
        sc[sel ^ 1][t] = x;
        __syncthreads();
        sel ^= 1;
    }
    const int base = (b == 0) ? 0 : sc[sel][b - 1];
    const int n = gcnt[b];
    __syncthreads();

    cnt[t] = 0;
    __syncthreads();
    const u32* seg = part + (size_t)b * BSTRIDE;
    for (int i = t; i < n; i += 512)
        atomicAdd(&cnt[seg[i] >> 17], 1);
    __syncthreads();
    int v = cnt[t];
    sc[0][t] = v;
    __syncthreads();
    sel = 0;
    for (int off = 1; off < 512; off <<= 1) {
        int x = sc[sel][t];
        if (t >= off) x += sc[sel][t - off];
        sc[sel ^ 1][t] = x;
        __syncthreads();
        sel ^= 1;
    }
    const int el = sc[sel][t] - v;
    const int g = b * 512 + t;
    if (g < NN) {
        row_off[g] = base + el;
        deg_inv[g] = (v > 0) ? 1.0f / (float)v : 0.0f;
    }
    if (b == NBUCK - 1 && t == 0) row_off[NN] = NE;
    cur[t] = el;
    __syncthreads();
    for (int i = t; i < n; i += 512) {
        u32 p = seg[i];
        int pos = atomicAdd(&cur[p >> 17], 1);
        int s2 = (int)(p & 0x1FFFFu);
        if (pos < BCAP) lsrc[pos] = s2;
        else srcs[base + pos] = s2;
    }
    __syncthreads();
    const int lim = (n < BCAP) ? n : BCAP;
    for (int i = t; i < lim; i += 512)
        srcs[base + i] = lsrc[i];
}

// ------- fp32 -> bf16 + fp8 (features), bf16 (weights), zero sentinel ------
__global__ void k_cvtall(const float* __restrict__ x, u16* __restrict__ xb,
                         u8* __restrict__ xb8, u8* __restrict__ hA8,
                         u8* __restrict__ hB8,
                         const float* __restrict__ w0, const float* __restrict__ w1,
                         const float* __restrict__ w2, const float* __restrict__ w3,
                         const float* __restrict__ w4, const float* __restrict__ w5,
                         u16* __restrict__ wbuf) {
    int i = blockIdx.x * blockDim.x + threadIdx.x;
    // zero the sentinel row (id = NN) of all three fp8 tables
    if (blockIdx.x == 0 && threadIdx.x < 48) {
        int wq = threadIdx.x & 15, wb_ = threadIdx.x >> 4;
        u8* tb = (wb_ == 0) ? xb8 : (wb_ == 1) ? hA8 : hB8;
        *(u32*)&tb[(size_t)NN * DD + wq * 4] = 0u;
    }
    int stride = gridDim.x * blockDim.x;
    const int total = NN * DD / 4;   // feature quads
    const int wt4 = 6 * 4096 / 4;    // weight quads
    for (; i < total + wt4; i += stride) {
        if (i < total) {
            float4 v = *(const float4*)&x[(size_t)i * 4];
            uint2 pk;
            pk.x = (u32)f2bf(v.x) | ((u32)f2bf(v.y) << 16);
            pk.y = (u32)f2bf(v.z) | ((u32)f2bf(v.w) << 16);
            ((uint2*)xb)[i] = pk;
            u32 lo = (u32)__builtin_amdgcn_cvt_pk_fp8_f32(v.x, v.y, 0, false);
            u32 q8 = (u32)__builtin_amdgcn_cvt_pk_fp8_f32(v.z, v.w, (int)lo, true);
            ((u32*)xb8)[i] = q8;
        } else {
            int k = (i - total) * 4;
            int m = k >> 12;
            const float* W = (m == 0) ? w0 : (m == 1) ? w1 : (m == 2) ? w2
                           : (m == 3) ? w3 : (m == 4) ? w4 : w5;
            float4 v = *(const float4*)&W[k & 4095];
            uint2 pk;
            pk.x = (u32)f2bf(v.x) | ((u32)f2bf(v.y) << 16);
            pk.y = (u32)f2bf(v.z) | ((u32)f2bf(v.w) << 16);
            ((uint2*)wbuf)[i - total] = pk;
        }
    }
}

// ---------------- fused layer: fp8 gather (mean) + dual bf16 MFMA ----------
// R8-proven structure: one INDEPENDENT wave per 16-node tile. Gather reads
// fp8 rows (64B, 4 rows/load via lane quarters, sentinel row NN = zeros).
// MFMA: agg via swizzled LDS transpose (bf16), x-term bf16, weights bf16.
// Epilogue writes bf16 + fp8 copies of the layer output.
__global__ void __launch_bounds__(256) k_fused(
    const u16* __restrict__ hin, const u8* __restrict__ hin8,
    u16* __restrict__ hout, u8* __restrict__ hout8,
    const u16* __restrict__ wb,   // [2][4096] bf16: Wl, Wr
    const float* __restrict__ bl,
    const int* __restrict__ row_off, const int* __restrict__ srcs,
    const float* __restrict__ deg_inv, int relu) {
    __shared__ int ids[4][64];
    __shared__ __align__(16) u8 aggT[4][2048];   // 16 rows x 128B, swizzled
    const int tid  = threadIdx.x;
    const int lane = tid & 63;
    const int wid  = tid >> 6;
    const int q    = lane >> 4;        // row quarter 0..3
    const int fl4  = (lane & 15) * 4;  // fp8 feature base (4 per lane)
    const int tile = blockIdx.x * 4 + wid;
    if (tile >= NTILE) return;
    const int n0 = tile * 16;

    // ---- gather phase: 16 nodes, wave-private, fp8 quad loads ----
    int beg = row_off[n0], end = row_off[n0 + 1];
    int myid = (beg + lane < end) ? srcs[beg + lane] : NN;

#define QUAD(J, A01, A23) { \
        int _id = ids[wid][(J) + q]; \
        u32 _v = *(const u32*)&hin8[(size_t)_id * DD + fl4]; \
        A01 += __builtin_amdgcn_cvt_pk_f32_fp8(_v, false); \
        A23 += __builtin_amdgcn_cvt_pk_f32_fp8(_v, true); }

    for (int j = 0; j < 16; ++j) {
        ids[wid][lane] = myid;
        __builtin_amdgcn_wave_barrier();
        // prefetch next node's ids
        int beg2 = 0, end2 = 0;
        if (j < 15) { beg2 = row_off[n0 + j + 1]; end2 = row_off[n0 + j + 2]; }
        myid = (beg2 + lane < end2) ? srcs[beg2 + lane] : NN;
        const float dinv = deg_inv[n0 + j];

        int deg = end - beg;
        int cnt = deg < 64 ? deg : 64;
        f32x2 a01 = {0.f, 0.f}, a23 = {0.f, 0.f};
        f32x2 b01 = {0.f, 0.f}, b23 = {0.f, 0.f};
        for (int jq = 0; jq < cnt; jq += 16) {   // 16 rows (incl. sentinels)
            QUAD(jq + 0,  a01, a23)
            QUAD(jq + 4,  b01, b23)
            QUAD(jq + 8,  a01, a23)
            QUAD(jq + 12, b01, b23)
        }
        for (int base2 = 64; base2 < deg; base2 += 64) {   // rare deg>64
            __builtin_amdgcn_wave_barrier();
            ids[wid][lane] = (beg + base2 + lane < end) ? srcs[beg + base2 + lane] : NN;
            __builtin_amdgcn_wave_barrier();
            int m = deg - base2; if (m > 64) m = 64;
            for (int jq = 0; jq < m; jq += 16) {
                QUAD(jq + 0,  a01, a23)
                QUAD(jq + 4,  b01, b23)
                QUAD(jq + 8,  a01, a23)
                QUAD(jq + 12, b01, b23)
            }
        }
        a01 += b01; a23 += b23;
        float s0 = a01.x, s1 = a01.y, s2 = a23.x, s3 = a23.y;
        s0 += __shfl_xor(s0, 32); s1 += __shfl_xor(s1, 32);
        s2 += __shfl_xor(s2, 32); s3 += __shfl_xor(s3, 32);
        s0 += __shfl_xor(s0, 16); s1 += __shfl_xor(s1, 16);
        s2 += __shfl_xor(s2, 16); s3 += __shfl_xor(s3, 16);
        s0 *= dinv; s1 *= dinv; s2 *= dinv; s3 *= dinv;
        if (lane < 16) {
            uint2 pk;
            pk.x = (u32)f2bf(s0) | ((u32)f2bf(s1) << 16);
            pk.y = (u32)f2bf(s2) | ((u32)f2bf(s3) << 16);
            *(uint2*)&aggT[wid][j * 128 + ((fl4 * 2) ^ ((j & 7) << 4))] = pk;
        }
        beg = beg2; end = end2;
        __builtin_amdgcn_wave_barrier();
    }
#undef QUAD

    asm volatile("" ::: "memory");   // keep weight loads out of gather phase

    // ---- MFMA phase: wave's own 16-node tile ----
    const int r = lane & 15, g = lane >> 4;
    f32x4 acc[4] = {};
#pragma unroll
    for (int kc = 0; kc < 2; ++kc) {
        const int cb = kc * 64 + g * 16;
        short8 aA = *(const short8*)&aggT[wid][r * 128 + (cb ^ ((r & 7) << 4))];
        short8 aH = *(const short8*)&hin[(size_t)(n0 + r) * DD + kc * 32 + g * 8];
#pragma unroll
        for (int ct = 0; ct < 4; ++ct) {
            const int wrow = (ct * 16 + r) * DD + kc * 32 + g * 8;
            short8 bA = *(const short8*)&wb[wrow];
            short8 bH = *(const short8*)&wb[4096 + wrow];
            acc[ct] = __builtin_amdgcn_mfma_f32_16x16x32_bf16(aA, bA, acc[ct], 0, 0, 0);
            acc[ct] = __builtin_amdgcn_mfma_f32_16x16x32_bf16(aH, bH, acc[ct], 0, 0, 0);
        }
    }
#pragma unroll
    for (int ct = 0; ct < 4; ++ct) {
        float bias = bl[ct * 16 + r];
#pragma unroll
        for (int e = 0; e < 4; ++e) {
            float v = acc[ct][e] + bias;
            if (relu) v = fmaxf(v, 0.f);
            const size_t node = (size_t)(n0 + g * 4 + e);
            hout[node * DD + ct * 16 + r] = f2bf(v);
            hout8[node * DD + ct * 16 + r] =
                (u8)((u32)__builtin_amdgcn_cvt_pk_fp8_f32(v, v, 0, false) & 0xffu);
        }
    }
}

// ---------------- graph readout ----------------
__global__ void k_reduce(const u16* __restrict__ h, const int* __restrict__ batch,
                         float* __restrict__ out) {
    const int lane = threadIdx.x & 63;
    const int wid  = threadIdx.x >> 6;
    const int gw   = blockIdx.x * 4 + wid;
    const int start = gw * 64;
    if (start >= NN) return;
    const int endn = (start + 64 < NN) ? start + 64 : NN;
    float acc = 0.f;
    int gcur = batch[start];
    for (int i = start; i < endn; ++i) {
        int g = batch[i];
        if (g != gcur) {
            atomicAdd(&out[gcur * DD + lane], acc);
            acc = 0.f;
            gcur = g;
        }
        acc += bf2f(h[(size_t)i * DD + lane]);
    }
    atomicAdd(&out[gcur * DD + lane], acc);
}

extern "C" void kernel_launch(void* const* d_in, const int* in_sizes, int n_in,
                              void* d_out, int out_size, void* d_ws, size_t ws_size,
                              hipStream_t stream) {
    const float* x     = (const float*)d_in[0];
    const int*   ei    = (const int*)d_in[1];
    const int*   batch = (const int*)d_in[2];
    const float* Wl[3] = {(const float*)d_in[3], (const float*)d_in[6], (const float*)d_in[9]};
    const float* bl[3] = {(const float*)d_in[4], (const float*)d_in[7], (const float*)d_in[10]};
    const float* Wr[3] = {(const float*)d_in[5], (const float*)d_in[8], (const float*)d_in[11]};
    float* out = (float*)d_out;

    char* ws = (char*)d_ws;
    size_t off = 0;
    auto alloc = [&](size_t bytes) -> void* {
        void* p = ws + off;
        off = (off + bytes + 255) & ~(size_t)255;
        return p;
    };
    int*   gcur    = (int*)  alloc(256 * 4);
    float* deg_inv = (float*)alloc((size_t)NN * 4);
    int*   row_off = (int*)  alloc(((size_t)NN + 1) * 4);
    int*   srcs    = (int*)  alloc((size_t)NE * 4);
    u16*   wbuf    = (u16*)  alloc((size_t)6 * 4096 * 2);
    u16*   xb      = (u16*)  alloc((size_t)NN * DD * 2);
    u16*   hAb     = (u16*)  alloc((size_t)NN * DD * 2);
    u16*   hBb     = (u16*)  alloc((size_t)NN * DD * 2);
    u8*    xb8     = (u8*)   alloc(((size_t)NN + 1) * DD);   // +1 sentinel row
    u8*    hA8     = (u8*)   alloc(((size_t)NN + 1) * DD);
    u8*    hB8     = (u8*)   alloc(((size_t)NN + 1) * DD);
    u32*   part    = (u32*)  alloc((size_t)NBUCK * BSTRIDE * 4);

    const int* e_src = ei;       // edge_index[0]
    const int* e_dst = ei + NE;  // edge_index[1]

    hipMemsetAsync(out, 0, (size_t)NG * DD * 4, stream);
    hipMemsetAsync(gcur, 0, 256 * 4, stream);

    k_part2<<<NBLK, 256, 0, stream>>>(e_src, e_dst, gcur, part);
    k_bucket2<<<NBUCK, 512, 0, stream>>>(part, gcur, row_off, srcs, deg_inv);
    k_cvtall<<<2048, 256, 0, stream>>>(x, xb, xb8, hA8, hB8,
                                       Wl[0], Wr[0], Wl[1], Wr[1], Wl[2], Wr[2], wbuf);

    k_fused<<<NBT, 256, 0, stream>>>(xb,  xb8, hAb, hA8, wbuf,            bl[0], row_off, srcs, deg_inv, 1);
    k_fused<<<NBT, 256, 0, stream>>>(hAb, hA8, hBb, hB8, wbuf + 1 * 8192, bl[1], row_off, srcs, deg_inv, 1);
    k_fused<<<NBT, 256, 0, stream>>>(hBb, hB8, hAb, xb8, wbuf + 2 * 8192, bl[2], row_off, srcs, deg_inv, 0);

    k_reduce<<<(NN / 64 + 4) / 4, 256, 0, stream>>>(hAb, batch, out);
}

// Round 12
// 174.984 us; speedup vs baseline: 1.8426x; 1.1571x over previous
//
#include <hip/hip_runtime.h>
#include <cstdint>
#include <cstddef>

#define NN 100000
#define NE 1600000
#define DD 64
#define NG 64

#define EPB 4096
#define NBLK ((NE + EPB - 1) / EPB)      // 391
#define NBUCK ((NN + 511) / 512)         // 196
#define BSTRIDE 12288                    // fixed per-bucket region in part[]
#define BCAP 10240
#define NTILE (NN / 16)                  // 6250
#define NBT ((NTILE + 3) / 4)            // 1563 blocks, 4 independent waves each

typedef unsigned short u16;
typedef unsigned int u32;
typedef unsigned char u8;
typedef short short8 __attribute__((ext_vector_type(8)));
typedef float f32x4 __attribute__((ext_vector_type(4)));
typedef float f32x2 __attribute__((ext_vector_type(2)));

__device__ __forceinline__ float bf2f(u16 h) {
    u32 u = ((u32)h) << 16;
    return __builtin_bit_cast(float, u);
}
__device__ __forceinline__ u16 f2bf(float f) {
    u32 u = __builtin_bit_cast(u32, f);
    u += 0x7fffu + ((u >> 16) & 1u);
    return (u16)(u >> 16);
}

// ---- CSR build, 2 kernels: bucket-partition with global atomic cursors ----
__global__ void __launch_bounds__(256) k_part2(const int* __restrict__ src,
                                               const int* __restrict__ dst,
                                               int* __restrict__ gcur,
                                               u32* __restrict__ part) {
    __shared__ int cnt[NBUCK];
    __shared__ int diff[NBUCK];
    __shared__ int cur[NBUCK];
    __shared__ int sc[2][256];
    __shared__ u32 pk[EPB];
    __shared__ u8  bk[EPB];
    const int t = threadIdx.x;
    const int blk = blockIdx.x;
    const int base = blk * EPB;
    const int n = ((base + EPB < NE) ? EPB : NE - base);
    for (int i = t; i < NBUCK; i += 256) cnt[i] = 0;
    __syncthreads();

    int myb[EPB / 256];
    u32 mypk[EPB / 256];
#pragma unroll
    for (int j = 0; j < EPB / 256; ++j) {
        int i = t + j * 256;
        bool ok = i < n;
        int d = ok ? dst[base + i] : 0;
        int s2 = ok ? src[base + i] : 0;
        int b = d >> 9;
        myb[j] = b;
        mypk[j] = ((u32)(d & 511) << 17) | (u32)s2;
        if (ok) atomicAdd(&cnt[b], 1);
    }
    __syncthreads();
    int v = (t < NBUCK) ? cnt[t] : 0;
    sc[0][t] = v;
    __syncthreads();
    int sel = 0;
    for (int off = 1; off < 256; off <<= 1) {
        int x = sc[sel][t];
        if (t >= off) x += sc[sel][t - off];
        sc[sel ^ 1][t] = x;
        __syncthreads();
        sel ^= 1;
    }
    if (t < NBUCK) {
        int e = sc[sel][t] - v;                         // local exclusive offset
        cur[t] = e;
        int gbase = (v > 0) ? atomicAdd(&gcur[t], v) : 0;
        diff[t] = t * BSTRIDE + gbase - e;
    }
    __syncthreads();
#pragma unroll
    for (int j = 0; j < EPB / 256; ++j) {
        int i = t + j * 256;
        if (i < n) {
            int pos = atomicAdd(&cur[myb[j]], 1);
            pk[pos] = mypk[j];
            bk[pos] = (u8)myb[j];
        }
    }
    __syncthreads();
    for (int p = t; p < n; p += 256)
        part[diff[bk[p]] + p] = pk[p];
}

__global__ void __launch_bounds__(512) k_bucket2(const u32* __restrict__ part,
                                                 const int* __restrict__ gcnt,
                                                 int* __restrict__ row_off,
                                                 int* __restrict__ srcs,
                                                 float* __restrict__ deg_inv) {
    __shared__ int cnt[512];
    __shared__ int cur[512];
    __shared__ int sc[2][512];
    __shared__ int lsrc[BCAP];
    const int b = blockIdx.x;
    const int t = threadIdx.x;

    // inclusive scan of bucket counts -> this bucket's dense base
    int gv = (t < NBUCK) ? gcnt[t] : 0;
    sc[0][t] = gv;
    __syncthreads();
    int sel = 0;
    for (int off = 1; off < 512; off <<= 1) {
        int x = sc[sel][t];
        if (t >= off) x += sc[sel][t - off];
        sc[sel ^ 1][t] = x;
        __syncthreads();
        sel ^= 1;
    }
    const int base = (b == 0) ? 0 : sc[sel][b - 1];
    const int n = gcnt[b];
    __syncthreads();

    cnt[t] = 0;
    __syncthreads();
    const u32* seg = part + (size_t)b * BSTRIDE;
    for (int i = t; i < n; i += 512)
        atomicAdd(&cnt[seg[i] >> 17], 1);
    __syncthreads();
    int v = cnt[t];
    sc[0][t] = v;
    __syncthreads();
    sel = 0;
    for (int off = 1; off < 512; off <<= 1) {
        int x = sc[sel][t];
        if (t >= off) x += sc[sel][t - off];
        sc[sel ^ 1][t] = x;
        __syncthreads();
        sel ^= 1;
    }
    const int el = sc[sel][t] - v;
    const int g = b * 512 + t;
    if (g < NN) {
        row_off[g] = base + el;
        deg_inv[g] = (v > 0) ? 1.0f / (float)v : 0.0f;
    }
    if (b == NBUCK - 1 && t == 0) row_off[NN] = NE;
    cur[t] = el;
    __syncthreads();
    for (int i = t; i < n; i += 512) {
        u32 p = seg[i];
        int pos = atomicAdd(&cur[p >> 17], 1);
        int s2 = (int)(p & 0x1FFFFu);
        if (pos < BCAP) lsrc[pos] = s2;
        else srcs[base + pos] = s2;
    }
    __syncthreads();
    const int lim = (n < BCAP) ? n : BCAP;
    for (int i = t; i < lim; i += 512)
        srcs[base + i] = lsrc[i];
}

// -- fp32 -> bf16 + fp8 (features), bf16 (weights), zero sentinel + out -----
__global__ void k_cvtall(const float* __restrict__ x, u16* __restrict__ xb,
                         u8* __restrict__ xb8, u8* __restrict__ hA8,
                         u8* __restrict__ hB8,
                         const float* __restrict__ w0, const float* __restrict__ w1,
                         const float* __restrict__ w2, const float* __restrict__ w3,
                         const float* __restrict__ w4, const float* __restrict__ w5,
                         u16* __restrict__ wbuf, float* __restrict__ gout) {
    int i0 = blockIdx.x * blockDim.x + threadIdx.x;
    // zero the graph-readout accumulator (4096 floats = 1024 float4)
    if (i0 < 1024) {
        float4 z = {0.f, 0.f, 0.f, 0.f};
        ((float4*)gout)[i0] = z;
    }
    // zero the sentinel row (id = NN) of all three fp8 tables
    if (blockIdx.x == 0 && threadIdx.x < 48) {
        int wq = threadIdx.x & 15, wb_ = threadIdx.x >> 4;
        u8* tb = (wb_ == 0) ? xb8 : (wb_ == 1) ? hA8 : hB8;
        *(u32*)&tb[(size_t)NN * DD + wq * 4] = 0u;
    }
    int i = i0;
    int stride = gridDim.x * blockDim.x;
    const int total = NN * DD / 4;   // feature quads
    const int wt4 = 6 * 4096 / 4;    // weight quads
    for (; i < total + wt4; i += stride) {
        if (i < total) {
            float4 v = *(const float4*)&x[(size_t)i * 4];
            uint2 pk;
            pk.x = (u32)f2bf(v.x) | ((u32)f2bf(v.y) << 16);
            pk.y = (u32)f2bf(v.z) | ((u32)f2bf(v.w) << 16);
            ((uint2*)xb)[i] = pk;
            u32 lo = (u32)__builtin_amdgcn_cvt_pk_fp8_f32(v.x, v.y, 0, false);
            u32 q8 = (u32)__builtin_amdgcn_cvt_pk_fp8_f32(v.z, v.w, (int)lo, true);
            ((u32*)xb8)[i] = q8;
        } else {
            int k = (i - total) * 4;
            int m = k >> 12;
            const float* W = (m == 0) ? w0 : (m == 1) ? w1 : (m == 2) ? w2
                           : (m == 3) ? w3 : (m == 4) ? w4 : w5;
            float4 v = *(const float4*)&W[k & 4095];
            uint2 pk;
            pk.x = (u32)f2bf(v.x) | ((u32)f2bf(v.y) << 16);
            pk.y = (u32)f2bf(v.z) | ((u32)f2bf(v.w) << 16);
            ((uint2*)wbuf)[i - total] = pk;
        }
    }
}

// ---------------- fused layer: fp8 gather (mean) + dual bf16 MFMA ----------
// R8-proven structure. mode 0: write bf16 + fp8 output planes (layers 1-2,
// with relu). mode 1 (final layer): write NOTHING -- reduce the output tile
// per-graph in-register (batch sorted -> tile almost always single-graph)
// and atomicAdd one partial per (column, tile) into gout.
__global__ void __launch_bounds__(256) k_fused(
    const u16* __restrict__ hin, const u8* __restrict__ hin8,
    u16* __restrict__ hout, u8* __restrict__ hout8,
    const u16* __restrict__ wb,   // [2][4096] bf16: Wl, Wr
    const float* __restrict__ bl,
    const int* __restrict__ row_off, const int* __restrict__ srcs,
    const float* __restrict__ deg_inv,
    const int* __restrict__ batch, float* __restrict__ gout,
    int relu, int mode) {
    __shared__ int ids[4][64];
    __shared__ __align__(16) u8 aggT[4][2048];   // 16 rows x 128B, swizzled
    const int tid  = threadIdx.x;
    const int lane = tid & 63;
    const int wid  = tid >> 6;
    const int q    = lane >> 4;        // row quarter 0..3
    const int fl4  = (lane & 15) * 4;  // fp8 feature base (4 per lane)
    const int tile = blockIdx.x * 4 + wid;
    if (tile >= NTILE) return;
    const int n0 = tile * 16;

    // ---- gather phase: 16 nodes, wave-private, fp8 quad loads ----
    int beg = row_off[n0], end = row_off[n0 + 1];
    int myid = (beg + lane < end) ? srcs[beg + lane] : NN;

#define QUAD(J, A01, A23) { \
        int _id = ids[wid][(J) + q]; \
        u32 _v = *(const u32*)&hin8[(size_t)_id * DD + fl4]; \
        A01 += __builtin_amdgcn_cvt_pk_f32_fp8(_v, false); \
        A23 += __builtin_amdgcn_cvt_pk_f32_fp8(_v, true); }

    for (int j = 0; j < 16; ++j) {
        ids[wid][lane] = myid;
        __builtin_amdgcn_wave_barrier();
        // prefetch next node's ids
        int beg2 = 0, end2 = 0;
        if (j < 15) { beg2 = row_off[n0 + j + 1]; end2 = row_off[n0 + j + 2]; }
        myid = (beg2 + lane < end2) ? srcs[beg2 + lane] : NN;
        const float dinv = deg_inv[n0 + j];

        int deg = end - beg;
        int cnt = deg < 64 ? deg : 64;
        f32x2 a01 = {0.f, 0.f}, a23 = {0.f, 0.f};
        f32x2 b01 = {0.f, 0.f}, b23 = {0.f, 0.f};
        for (int jq = 0; jq < cnt; jq += 16) {   // 16 rows (incl. sentinels)
            QUAD(jq + 0,  a01, a23)
            QUAD(jq + 4,  b01, b23)
            QUAD(jq + 8,  a01, a23)
            QUAD(jq + 12, b01, b23)
        }
        for (int base2 = 64; base2 < deg; base2 += 64) {   // rare deg>64
            __builtin_amdgcn_wave_barrier();
            ids[wid][lane] = (beg + base2 + lane < end) ? srcs[beg + base2 + lane] : NN;
            __builtin_amdgcn_wave_barrier();
            int m = deg - base2; if (m > 64) m = 64;
            for (int jq = 0; jq < m; jq += 16) {
                QUAD(jq + 0,  a01, a23)
                QUAD(jq + 4,  b01, b23)
                QUAD(jq + 8,  a01, a23)
                QUAD(jq + 12, b01, b23)
            }
        }
        a01 += b01; a23 += b23;
        float s0 = a01.x, s1 = a01.y, s2 = a23.x, s3 = a23.y;
        s0 += __shfl_xor(s0, 32); s1 += __shfl_xor(s1, 32);
        s2 += __shfl_xor(s2, 32); s3 += __shfl_xor(s3, 32);
        s0 += __shfl_xor(s0, 16); s1 += __shfl_xor(s1, 16);
        s2 += __shfl_xor(s2, 16); s3 += __shfl_xor(s3, 16);
        s0 *= dinv; s1 *= dinv; s2 *= dinv; s3 *= dinv;
        if (lane < 16) {
            uint2 pk;
            pk.x = (u32)f2bf(s0) | ((u32)f2bf(s1) << 16);
            pk.y = (u32)f2bf(s2) | ((u32)f2bf(s3) << 16);
            *(uint2*)&aggT[wid][j * 128 + ((fl4 * 2) ^ ((j & 7) << 4))] = pk;
        }
        beg = beg2; end = end2;
        __builtin_amdgcn_wave_barrier();
    }
#undef QUAD

    asm volatile("" ::: "memory");   // keep weight loads out of gather phase

    // ---- MFMA phase: wave's own 16-node tile ----
    const int r = lane & 15, g = lane >> 4;
    f32x4 acc[4] = {};
#pragma unroll
    for (int kc = 0; kc < 2; ++kc) {
        const int cb = kc * 64 + g * 16;
        short8 aA = *(const short8*)&aggT[wid][r * 128 + (cb ^ ((r & 7) << 4))];
        short8 aH = *(const short8*)&hin[(size_t)(n0 + r) * DD + kc * 32 + g * 8];
#pragma unroll
        for (int ct = 0; ct < 4; ++ct) {
            const int wrow = (ct * 16 + r) * DD + kc * 32 + g * 8;
            short8 bA = *(const short8*)&wb[wrow];
            short8 bH = *(const short8*)&wb[4096 + wrow];
            acc[ct] = __builtin_amdgcn_mfma_f32_16x16x32_bf16(aA, bA, acc[ct], 0, 0, 0);
            acc[ct] = __builtin_amdgcn_mfma_f32_16x16x32_bf16(aH, bH, acc[ct], 0, 0, 0);
        }
    }
    if (mode == 0) {
#pragma unroll
        for (int ct = 0; ct < 4; ++ct) {
            float bias = bl[ct * 16 + r];
#pragma unroll
            for (int e = 0; e < 4; ++e) {
                float v = acc[ct][e] + bias;
                if (relu) v = fmaxf(v, 0.f);
                const size_t node = (size_t)(n0 + g * 4 + e);
                hout[node * DD + ct * 16 + r] = f2bf(v);
                hout8[node * DD + ct * 16 + r] =
                    (u8)((u32)__builtin_amdgcn_cvt_pk_fp8_f32(v, v, 0, false) & 0xffu);
            }
        }
    } else {
        // fused graph readout (final layer, no relu)
        const int bfirst = batch[n0];
        const int blast  = batch[n0 + 15];
        if (bfirst == blast) {
#pragma unroll
            for (int ct = 0; ct < 4; ++ct) {
                float bias = bl[ct * 16 + r];
                float s = (acc[ct][0] + acc[ct][1]) + (acc[ct][2] + acc[ct][3])
                        + 4.f * bias;
                s += __shfl_xor(s, 16);
                s += __shfl_xor(s, 32);
                if (lane < 16)
                    atomicAdd(&gout[bfirst * DD + ct * 16 + r], s);
            }
        } else {
            int bg[4];
#pragma unroll
            for (int e = 0; e < 4; ++e) bg[e] = batch[n0 + g * 4 + e];
#pragma unroll
            for (int ct = 0; ct < 4; ++ct) {
                float bias = bl[ct * 16 + r];
#pragma unroll
                for (int e = 0; e < 4; ++e)
                    atomicAdd(&gout[bg[e] * DD + ct * 16 + r], acc[ct][e] + bias);
            }
        }
    }
}

extern "C" void kernel_launch(void* const* d_in, const int* in_sizes, int n_in,
                              void* d_out, int out_size, void* d_ws, size_t ws_size,
                              hipStream_t stream) {
    const float* x     = (const float*)d_in[0];
    const int*   ei    = (const int*)d_in[1];
    const int*   batch = (const int*)d_in[2];
    const float* Wl[3] = {(const float*)d_in[3], (const float*)d_in[6], (const float*)d_in[9]};
    const float* bl[3] = {(const float*)d_in[4], (const float*)d_in[7], (const float*)d_in[10]};
    const float* Wr[3] = {(const float*)d_in[5], (const float*)d_in[8], (const float*)d_in[11]};
    float* out = (float*)d_out;

    char* ws = (char*)d_ws;
    size_t off = 0;
    auto alloc = [&](size_t bytes) -> void* {
        void* p = ws + off;
        off = (off + bytes + 255) & ~(size_t)255;
        return p;
    };
    int*   gcur    = (int*)  alloc(256 * 4);
    float* deg_inv = (float*)alloc((size_t)NN * 4);
    int*   row_off = (int*)  alloc(((size_t)NN + 1) * 4);
    int*   srcs    = (int*)  alloc((size_t)NE * 4);
    u16*   wbuf    = (u16*)  alloc((size_t)6 * 4096 * 2);
    u16*   xb      = (u16*)  alloc((size_t)NN * DD * 2);
    u16*   hAb     = (u16*)  alloc((size_t)NN * DD * 2);
    u16*   hBb     = (u16*)  alloc((size_t)NN * DD * 2);
    u8*    xb8     = (u8*)   alloc(((size_t)NN + 1) * DD);   // +1 sentinel row
    u8*    hA8     = (u8*)   alloc(((size_t)NN + 1) * DD);
    u8*    hB8     = (u8*)   alloc(((size_t)NN + 1) * DD);
    u32*   part    = (u32*)  alloc((size_t)NBUCK * BSTRIDE * 4);

    const int* e_src = ei;       // edge_index[0]
    const int* e_dst = ei + NE;  // edge_index[1]

    hipMemsetAsync(gcur, 0, 256 * 4, stream);

    k_part2<<<NBLK, 256, 0, stream>>>(e_src, e_dst, gcur, part);
    k_bucket2<<<NBUCK, 512, 0, stream>>>(part, gcur, row_off, srcs, deg_inv);
    k_cvtall<<<2048, 256, 0, stream>>>(x, xb, xb8, hA8, hB8,
                                       Wl[0], Wr[0], Wl[1], Wr[1], Wl[2], Wr[2],
                                       wbuf, out);

    k_fused<<<NBT, 256, 0, stream>>>(xb,  xb8, hAb, hA8, wbuf,
                                     bl[0], row_off, srcs, deg_inv, batch, out, 1, 0);
    k_fused<<<NBT, 256, 0, stream>>>(hAb, hA8, hBb, hB8, wbuf + 1 * 8192,
                                     bl[1], row_off, srcs, deg_inv, batch, out, 1, 0);
    k_fused<<<NBT, 256, 0, stream>>>(hBb, hB8, hAb, xb8, wbuf + 2 * 8192,
                                     bl[2], row_off, srcs, deg_inv, batch, out, 0, 1);
}

// Round 13
// 160.407 us; speedup vs baseline: 2.0100x; 1.0909x over previous
//
#include <hip/hip_runtime.h>
#include <cstdint>
#include <cstddef>

#define NN 100000
#define NE 1600000
#define DD 64
#define NG 64

#define EPB 4096
#define NBLK ((NE + EPB - 1) / EPB)      // 391
#define NBUCK ((NN + 511) / 512)         // 196
#define BSTRIDE 12288                    // fixed per-bucket region in part[]
#define BCAP 10240
#define NTILE (NN / 16)                  // 6250
#define NBT ((NTILE + 3) / 4)            // 1563 blocks, 4 independent waves each

typedef unsigned short u16;
typedef unsigned int u32;
typedef unsigned char u8;
typedef short short8 __attribute__((ext_vector_type(8)));
typedef float f32x4 __attribute__((ext_vector_type(4)));
typedef float f32x2 __attribute__((ext_vector_type(2)));

__device__ __forceinline__ float bf2f(u16 h) {
    u32 u = ((u32)h) << 16;
    return __builtin_bit_cast(float, u);
}
__device__ __forceinline__ u16 f2bf(float f) {
    u32 u = __builtin_bit_cast(u32, f);
    u += 0x7fffu + ((u >> 16) & 1u);
    return (u16)(u >> 16);
}

// -- fp32 -> bf16 + fp8 (features), bf16 (weights); zero sentinel, out, gcur-
__global__ void k_cvtall(const float* __restrict__ x, u16* __restrict__ xb,
                         u8* __restrict__ xb8, u8* __restrict__ hA8,
                         u8* __restrict__ hB8,
                         const float* __restrict__ w0, const float* __restrict__ w1,
                         const float* __restrict__ w2, const float* __restrict__ w3,
                         const float* __restrict__ w4, const float* __restrict__ w5,
                         u16* __restrict__ wbuf, float* __restrict__ gout,
                         int* __restrict__ gcur) {
    int i0 = blockIdx.x * blockDim.x + threadIdx.x;
    // zero the graph-readout accumulator (4096 floats = 1024 float4)
    if (i0 < 1024) {
        float4 z = {0.f, 0.f, 0.f, 0.f};
        ((float4*)gout)[i0] = z;
    }
    if (blockIdx.x == 0) {
        // zero the bucket cursors (consumed by k_part2, launched after us)
        if (threadIdx.x < 256) gcur[threadIdx.x] = 0;
        // zero the sentinel row (id = NN) of all three fp8 tables
        if (threadIdx.x < 48) {
            int wq = threadIdx.x & 15, wb_ = threadIdx.x >> 4;
            u8* tb = (wb_ == 0) ? xb8 : (wb_ == 1) ? hA8 : hB8;
            *(u32*)&tb[(size_t)NN * DD + wq * 4] = 0u;
        }
    }
    int i = i0;
    int stride = gridDim.x * blockDim.x;
    const int total = NN * DD / 4;   // feature quads
    const int wt4 = 6 * 4096 / 4;    // weight quads
    for (; i < total + wt4; i += stride) {
        if (i < total) {
            float4 v = *(const float4*)&x[(size_t)i * 4];
            uint2 pk;
            pk.x = (u32)f2bf(v.x) | ((u32)f2bf(v.y) << 16);
            pk.y = (u32)f2bf(v.z) | ((u32)f2bf(v.w) << 16);
            ((uint2*)xb)[i] = pk;
            u32 lo = (u32)__builtin_amdgcn_cvt_pk_fp8_f32(v.x, v.y, 0, false);
            u32 q8 = (u32)__builtin_amdgcn_cvt_pk_fp8_f32(v.z, v.w, (int)lo, true);
            ((u32*)xb8)[i] = q8;
        } else {
            int k = (i - total) * 4;
            int m = k >> 12;
            const float* W = (m == 0) ? w0 : (m == 1) ? w1 : (m == 2) ? w2
                           : (m == 3) ? w3 : (m == 4) ? w4 : w5;
            float4 v = *(const float4*)&W[k & 4095];
            uint2 pk;
            pk.x = (u32)f2bf(v.x) | ((u32)f2bf(v.y) << 16);
            pk.y = (u32)f2bf(v.z) | ((u32)f2bf(v.w) << 16);
            ((uint2*)wbuf)[i - total] = pk;
        }
    }
}

// ---- CSR build, 2 kernels: bucket-partition with global atomic cursors ----
// k_part2: contiguous 16-edge chunk per thread, int4-vectorized loads.
__global__ void __launch_bounds__(256) k_part2(const int* __restrict__ src,
                                               const int* __restrict__ dst,
                                               int* __restrict__ gcur,
                                               u32* __restrict__ part) {
    __shared__ int cnt[NBUCK];
    __shared__ int diff[NBUCK];
    __shared__ int cur[NBUCK];
    __shared__ int sc[2][256];
    __shared__ u32 pk[EPB];
    __shared__ u8  bk[EPB];
    const int t = threadIdx.x;
    const int blk = blockIdx.x;
    const int base = blk * EPB;
    const int n = ((base + EPB < NE) ? EPB : NE - base);
    for (int i = t; i < NBUCK; i += 256) cnt[i] = 0;
    __syncthreads();

    const int e0 = t * 16;   // this thread's contiguous chunk
    int myb[16];
    u32 mypk[16];
    if (e0 + 16 <= n) {
        int4 d4[4], s4[4];
#pragma unroll
        for (int j = 0; j < 4; ++j) {
            d4[j] = *(const int4*)&dst[base + e0 + j * 4];
            s4[j] = *(const int4*)&src[base + e0 + j * 4];
        }
#pragma unroll
        for (int j = 0; j < 16; ++j) {
            int d  = ((const int*)d4)[j];
            int s2 = ((const int*)s4)[j];
            myb[j] = d >> 9;
            mypk[j] = ((u32)(d & 511) << 17) | (u32)s2;
            atomicAdd(&cnt[myb[j]], 1);
        }
    } else {
#pragma unroll
        for (int j = 0; j < 16; ++j) {
            int i = e0 + j;
            bool ok = i < n;
            int d  = ok ? dst[base + i] : 0;
            int s2 = ok ? src[base + i] : 0;
            myb[j] = d >> 9;
            mypk[j] = ((u32)(d & 511) << 17) | (u32)s2;
            if (ok) atomicAdd(&cnt[myb[j]], 1);
        }
    }
    __syncthreads();
    int v = (t < NBUCK) ? cnt[t] : 0;
    sc[0][t] = v;
    __syncthreads();
    int sel = 0;
    for (int off = 1; off < 256; off <<= 1) {
        int x = sc[sel][t];
        if (t >= off) x += sc[sel][t - off];
        sc[sel ^ 1][t] = x;
        __syncthreads();
        sel ^= 1;
    }
    if (t < NBUCK) {
        int e = sc[sel][t] - v;                         // local exclusive offset
        cur[t] = e;
        int gbase = (v > 0) ? atomicAdd(&gcur[t], v) : 0;
        diff[t] = t * BSTRIDE + gbase - e;
    }
    __syncthreads();
    if (e0 + 16 <= n) {
#pragma unroll
        for (int j = 0; j < 16; ++j) {
            int pos = atomicAdd(&cur[myb[j]], 1);
            pk[pos] = mypk[j];
            bk[pos] = (u8)myb[j];
        }
    } else {
        for (int j = 0; j < 16; ++j) {
            if (e0 + j < n) {
                int pos = atomicAdd(&cur[myb[j]], 1);
                pk[pos] = mypk[j];
                bk[pos] = (u8)myb[j];
            }
        }
    }
    __syncthreads();
    for (int p = t; p < n; p += 256)
        part[diff[bk[p]] + p] = pk[p];
}

// k_bucket2: per bucket, dense base via LDS scan of cursor counts, then
// per-dst counts -> row_off/deg_inv, LDS scatter of srcs, coalesced flush.
// Both segment passes read uint4 (4 edges/load).
__global__ void __launch_bounds__(512) k_bucket2(const u32* __restrict__ part,
                                                 const int* __restrict__ gcnt,
                                                 int* __restrict__ row_off,
                                                 int* __restrict__ srcs,
                                                 float* __restrict__ deg_inv) {
    __shared__ int cnt[512];
    __shared__ int cur[512];
    __shared__ int sc[2][512];
    __shared__ int lsrc[BCAP];
    const int b = blockIdx.x;
    const int t = threadIdx.x;

    // inclusive scan of bucket counts -> this bucket's dense base
    int gv = (t < NBUCK) ? gcnt[t] : 0;
    sc[0][t] = gv;
    __syncthreads();
    int sel = 0;
    for (int off = 1; off < 512; off <<= 1) {
        int x = sc[sel][t];
        if (t >= off) x += sc[sel][t - off];
        sc[sel ^ 1][t] = x;
        __syncthreads();
        sel ^= 1;
    }
    const int base = (b == 0) ? 0 : sc[sel][b - 1];
    const int n = gcnt[b];
    __syncthreads();

    cnt[t] = 0;
    __syncthreads();
    const u32* seg = part + (size_t)b * BSTRIDE;
    const int n4 = n >> 2;
    for (int i = t; i < n4; i += 512) {
        uint4 p4 = ((const uint4*)seg)[i];
        atomicAdd(&cnt[p4.x >> 17], 1);
        atomicAdd(&cnt[p4.y >> 17], 1);
        atomicAdd(&cnt[p4.z >> 17], 1);
        atomicAdd(&cnt[p4.w >> 17], 1);
    }
    for (int i = (n4 << 2) + t; i < n; i += 512)
        atomicAdd(&cnt[seg[i] >> 17], 1);
    __syncthreads();
    int v = cnt[t];
    sc[0][t] = v;
    __syncthreads();
    sel = 0;
    for (int off = 1; off < 512; off <<= 1) {
        int x = sc[sel][t];
        if (t >= off) x += sc[sel][t - off];
        sc[sel ^ 1][t] = x;
        __syncthreads();
        sel ^= 1;
    }
    const int el = sc[sel][t] - v;
    const int g = b * 512 + t;
    if (g < NN) {
        row_off[g] = base + el;
        deg_inv[g] = (v > 0) ? 1.0f / (float)v : 0.0f;
    }
    if (b == NBUCK - 1 && t == 0) row_off[NN] = NE;
    cur[t] = el;
    __syncthreads();
    for (int i = t; i < n4; i += 512) {
        uint4 p4 = ((const uint4*)seg)[i];
#pragma unroll
        for (int j = 0; j < 4; ++j) {
            u32 p = (j == 0) ? p4.x : (j == 1) ? p4.y : (j == 2) ? p4.z : p4.w;
            int pos = atomicAdd(&cur[p >> 17], 1);
            int s2 = (int)(p & 0x1FFFFu);
            if (pos < BCAP) lsrc[pos] = s2;
            else srcs[base + pos] = s2;
        }
    }
    for (int i = (n4 << 2) + t; i < n; i += 512) {
        u32 p = seg[i];
        int pos = atomicAdd(&cur[p >> 17], 1);
        int s2 = (int)(p & 0x1FFFFu);
        if (pos < BCAP) lsrc[pos] = s2;
        else srcs[base + pos] = s2;
    }
    __syncthreads();
    const int lim = (n < BCAP) ? n : BCAP;
    for (int i = t; i < lim; i += 512)
        srcs[base + i] = lsrc[i];
}

// ---------------- fused layer: fp8 gather (mean) + dual bf16 MFMA ----------
// R8-proven structure. mode 0: write bf16 + fp8 output planes (layers 1-2,
// with relu). mode 1 (final layer): write NOTHING -- reduce the output tile
// per-graph in-register (batch sorted -> tile almost always single-graph)
// and atomicAdd one partial per (column, tile) into gout.
__global__ void __launch_bounds__(256) k_fused(
    const u16* __restrict__ hin, const u8* __restrict__ hin8,
    u16* __restrict__ hout, u8* __restrict__ hout8,
    const u16* __restrict__ wb,   // [2][4096] bf16: Wl, Wr
    const float* __restrict__ bl,
    const int* __restrict__ row_off, const int* __restrict__ srcs,
    const float* __restrict__ deg_inv,
    const int* __restrict__ batch, float* __restrict__ gout,
    int relu, int mode) {
    __shared__ int ids[4][64];
    __shared__ __align__(16) u8 aggT[4][2048];   // 16 rows x 128B, swizzled
    const int tid  = threadIdx.x;
    const int lane = tid & 63;
    const int wid  = tid >> 6;
    const int q    = lane >> 4;        // row quarter 0..3
    const int fl4  = (lane & 15) * 4;  // fp8 feature base (4 per lane)
    const int tile = blockIdx.x * 4 + wid;
    if (tile >= NTILE) return;
    const int n0 = tile * 16;

    // ---- gather phase: 16 nodes, wave-private, fp8 quad loads ----
    int beg = row_off[n0], end = row_off[n0 + 1];
    int myid = (beg + lane < end) ? srcs[beg + lane] : NN;

#define QUAD(J, A01, A23) { \
        int _id = ids[wid][(J) + q]; \
        u32 _v = *(const u32*)&hin8[(size_t)_id * DD + fl4]; \
        A01 += __builtin_amdgcn_cvt_pk_f32_fp8(_v, false); \
        A23 += __builtin_amdgcn_cvt_pk_f32_fp8(_v, true); }

    for (int j = 0; j < 16; ++j) {
        ids[wid][lane] = myid;
        __builtin_amdgcn_wave_barrier();
        // prefetch next node's ids
        int beg2 = 0, end2 = 0;
        if (j < 15) { beg2 = row_off[n0 + j + 1]; end2 = row_off[n0 + j + 2]; }
        myid = (beg2 + lane < end2) ? srcs[beg2 + lane] : NN;
        const float dinv = deg_inv[n0 + j];

        int deg = end - beg;
        int cnt = deg < 64 ? deg : 64;
        f32x2 a01 = {0.f, 0.f}, a23 = {0.f, 0.f};
        f32x2 b01 = {0.f, 0.f}, b23 = {0.f, 0.f};
        for (int jq = 0; jq < cnt; jq += 16) {   // 16 rows (incl. sentinels)
            QUAD(jq + 0,  a01, a23)
            QUAD(jq + 4,  b01, b23)
            QUAD(jq + 8,  a01, a23)
            QUAD(jq + 12, b01, b23)
        }
        for (int base2 = 64; base2 < deg; base2 += 64) {   // rare deg>64
            __builtin_amdgcn_wave_barrier();
            ids[wid][lane] = (beg + base2 + lane < end) ? srcs[beg + base2 + lane] : NN;
            __builtin_amdgcn_wave_barrier();
            int m = deg - base2; if (m > 64) m = 64;
            for (int jq = 0; jq < m; jq += 16) {
                QUAD(jq + 0,  a01, a23)
                QUAD(jq + 4,  b01, b23)
                QUAD(jq + 8,  a01, a23)
                QUAD(jq + 12, b01, b23)
            }
        }
        a01 += b01; a23 += b23;
        float s0 = a01.x, s1 = a01.y, s2 = a23.x, s3 = a23.y;
        s0 += __shfl_xor(s0, 32); s1 += __shfl_xor(s1, 32);
        s2 += __shfl_xor(s2, 32); s3 += __shfl_xor(s3, 32);
        s0 += __shfl_xor(s0, 16); s1 += __shfl_xor(s1, 16);
        s2 += __shfl_xor(s2, 16); s3 += __shfl_xor(s3, 16);
        s0 *= dinv; s1 *= dinv; s2 *= dinv; s3 *= dinv;
        if (lane < 16) {
            uint2 pk;
            pk.x = (u32)f2bf(s0) | ((u32)f2bf(s1) << 16);
            pk.y = (u32)f2bf(s2) | ((u32)f2bf(s3) << 16);
            *(uint2*)&aggT[wid][j * 128 + ((fl4 * 2) ^ ((j & 7) << 4))] = pk;
        }
        beg = beg2; end = end2;
        __builtin_amdgcn_wave_barrier();
    }
#undef QUAD

    asm volatile("" ::: "memory");   // keep weight loads out of gather phase

    // ---- MFMA phase: wave's own 16-node tile ----
    const int r = lane & 15, g = lane >> 4;
    f32x4 acc[4] = {};
#pragma unroll
    for (int kc = 0; kc < 2; ++kc) {
        const int cb = kc * 64 + g * 16;
        short8 aA = *(const short8*)&aggT[wid][r * 128 + (cb ^ ((r & 7) << 4))];
        short8 aH = *(const short8*)&hin[(size_t)(n0 + r) * DD + kc * 32 + g * 8];
#pragma unroll
        for (int ct = 0; ct < 4; ++ct) {
            const int wrow = (ct * 16 + r) * DD + kc * 32 + g * 8;
            short8 bA = *(const short8*)&wb[wrow];
            short8 bH = *(const short8*)&wb[4096 + wrow];
            acc[ct] = __builtin_amdgcn_mfma_f32_16x16x32_bf16(aA, bA, acc[ct], 0, 0, 0);
            acc[ct] = __builtin_amdgcn_mfma_f32_16x16x32_bf16(aH, bH, acc[ct], 0, 0, 0);
        }
    }
    if (mode == 0) {
#pragma unroll
        for (int ct = 0; ct < 4; ++ct) {
            float bias = bl[ct * 16 + r];
#pragma unroll
            for (int e = 0; e < 4; ++e) {
                float v = acc[ct][e] + bias;
                if (relu) v = fmaxf(v, 0.f);
                const size_t node = (size_t)(n0 + g * 4 + e);
                hout[node * DD + ct * 16 + r] = f2bf(v);
                hout8[node * DD + ct * 16 + r] =
                    (u8)((u32)__builtin_amdgcn_cvt_pk_fp8_f32(v, v, 0, false) & 0xffu);
            }
        }
    } else {
        // fused graph readout (final layer, no relu)
        const int bfirst = batch[n0];
        const int blast  = batch[n0 + 15];
        if (bfirst == blast) {
#pragma unroll
            for (int ct = 0; ct < 4; ++ct) {
                float bias = bl[ct * 16 + r];
                float s = (acc[ct][0] + acc[ct][1]) + (acc[ct][2] + acc[ct][3])
                        + 4.f * bias;
                s += __shfl_xor(s, 16);
                s += __shfl_xor(s, 32);
                if (lane < 16)
                    atomicAdd(&gout[bfirst * DD + ct * 16 + r], s);
            }
        } else {
            int bg[4];
#pragma unroll
            for (int e = 0; e < 4; ++e) bg[e] = batch[n0 + g * 4 + e];
#pragma unroll
            for (int ct = 0; ct < 4; ++ct) {
                float bias = bl[ct * 16 + r];
#pragma unroll
                for (int e = 0; e < 4; ++e)
                    atomicAdd(&gout[bg[e] * DD + ct * 16 + r], acc[ct][e] + bias);
            }
        }
    }
}

extern "C" void kernel_launch(void* const* d_in, const int* in_sizes, int n_in,
                              void* d_out, int out_size, void* d_ws, size_t ws_size,
                              hipStream_t stream) {
    const float* x     = (const float*)d_in[0];
    const int*   ei    = (const int*)d_in[1];
    const int*   batch = (const int*)d_in[2];
    const float* Wl[3] = {(const float*)d_in[3], (const float*)d_in[6], (const float*)d_in[9]};
    const float* bl[3] = {(const float*)d_in[4], (const float*)d_in[7], (const float*)d_in[10]};
    const float* Wr[3] = {(const float*)d_in[5], (const float*)d_in[8], (const float*)d_in[11]};
    float* out = (float*)d_out;

    char* ws = (char*)d_ws;
    size_t off = 0;
    auto alloc = [&](size_t bytes) -> void* {
        void* p = ws + off;
        off = (off + bytes + 255) & ~(size_t)255;
        return p;
    };
    int*   gcur    = (int*)  alloc(256 * 4);
    float* deg_inv = (float*)alloc((size_t)NN * 4);
    int*   row_off = (int*)  alloc(((size_t)NN + 1) * 4);
    int*   srcs    = (int*)  alloc((size_t)NE * 4);
    u16*   wbuf    = (u16*)  alloc((size_t)6 * 4096 * 2);
    u16*   xb      = (u16*)  alloc((size_t)NN * DD * 2);
    u16*   hAb     = (u16*)  alloc((size_t)NN * DD * 2);
    u16*   hBb     = (u16*)  alloc((size_t)NN * DD * 2);
    u8*    xb8     = (u8*)   alloc(((size_t)NN + 1) * DD);   // +1 sentinel row
    u8*    hA8     = (u8*)   alloc(((size_t)NN + 1) * DD);
    u8*    hB8     = (u8*)   alloc(((size_t)NN + 1) * DD);
    u32*   part    = (u32*)  alloc((size_t)NBUCK * BSTRIDE * 4);

    const int* e_src = ei;       // edge_index[0]
    const int* e_dst = ei + NE;  // edge_index[1]

    k_cvtall<<<2048, 256, 0, stream>>>(x, xb, xb8, hA8, hB8,
                                       Wl[0], Wr[0], Wl[1], Wr[1], Wl[2], Wr[2],
                                       wbuf, out, gcur);
    k_part2<<<NBLK, 256, 0, stream>>>(e_src, e_dst, gcur, part);
    k_bucket2<<<NBUCK, 512, 0, stream>>>(part, gcur, row_off, srcs, deg_inv);

    k_fused<<<NBT, 256, 0, stream>>>(xb,  xb8, hAb, hA8, wbuf,
                                     bl[0], row_off, srcs, deg_inv, batch, out, 1, 0);
    k_fused<<<NBT, 256, 0, stream>>>(hAb, hA8, hBb, hB8, wbuf + 1 * 8192,
                                     bl[1], row_off, srcs, deg_inv, batch, out, 1, 0);
    k_fused<<<NBT, 256, 0, stream>>>(hBb, hB8, hAb, xb8, wbuf + 2 * 8192,
                                     bl[2], row_off, srcs, deg_inv, batch, out, 0, 1);
}